// Round 16
// baseline (138.588 us; speedup 1.0000x reference)
//
#include <hip/hip_runtime.h>
#include <hip/hip_bf16.h>
#include <stdint.h>

#define NB 2048      // groups
#define D 128
#define NPG 91

typedef __attribute__((ext_vector_type(8))) short short8;
typedef __attribute__((ext_vector_type(4))) float f32x4;

__device__ __forceinline__ unsigned bf16pk(float a, float b) {
  __hip_bfloat162 h2 = __float22bfloat162_rn(make_float2(a, b));
  return *reinterpret_cast<unsigned*>(&h2);   // v_cvt_pk_bf16_f32
}

__device__ __forceinline__ float sigf(float x) {
  float e = __expf(-x);
  return __builtin_amdgcn_rcpf(1.0f + e);     // v_rcp_f32, ~1ulp
}

// K0: pack Wu (units 0..11) and Wv (units 12..23) transposed to bf16 in MFMA
// A-fragment order (flipped GEMM):
// wpk[u*512 + row*4 + g] (uint4) = 8 bf16 of W[o][kk*32+g*8 + 0..7][row],
// u = o*4+kk (Wu) or 12 + o*4+kk (Wv).
__global__ void w_pack(const float* __restrict__ Wu,
                       const float* __restrict__ Wv,
                       uint4* __restrict__ wpk) {
  const int u = blockIdx.x;
  const float* W = (u < 12) ? Wu : Wv;
  const int uu = (u < 12) ? u : u - 12;
  const int o = uu >> 2, kk = uu & 3;
  const int t = threadIdx.x;
  #pragma unroll
  for (int i = 0; i < 2; ++i) {
    int idx = i * 256 + t;              // 0..511
    int row = idx >> 2, g = idx & 3;
    const float* src = W + (size_t)o * D * D + (kk * 32 + g * 8) * D + row;
    uint4 pk;
    pk.x = bf16pk(src[0 * D], src[1 * D]);
    pk.y = bf16pk(src[2 * D], src[3 * D]);
    pk.z = bf16pk(src[4 * D], src[5 * D]);
    pk.w = bf16pk(src[6 * D], src[7 * D]);
    wpk[(size_t)u * 512 + idx] = pk;
  }
}

// K1: one block per group, 512 threads / 8 waves, (512,8) [<=44 total regs
// proven no-spill, 4 blocks/CU]. Wave q owns h-tile q (R14 layout).
// e-reduction via ds_add_f32 into ep[3][96] (fire-and-forget; replaces the
// 36-shfl dependent chain + the softmax-side 8-way gather). fv bias
// in-register; barrier-free o-loop with s_setprio(1) around the MFMA cluster;
// T14 prefetch of weighted-sum loads.
__global__ __launch_bounds__(512, 8) void sihg_main(
    const float* __restrict__ feats,
    const uint4* __restrict__ wpk,
    const float* __restrict__ bu,
    const float* __restrict__ We,
    float* __restrict__ out) {
  __shared__ __align__(16) char lds[29952];
  constexpr int FE_OFF  = 0;      // 24576: feats bf16 [96]x256B swizzled; later part[8][384]
  constexpr int BUL_OFF = 24576;  // 1536: f32[3][128] bu
  constexpr int WEL_OFF = 26112;  // 1536: f32[3][128] We
  constexpr int EP_OFF  = 27648;  // 1152: f32[3][96] e (atomic accumulation)
  constexpr int AL_OFF  = 28800;  // 1152: f32[3][96] alpha

  const int t = threadIdx.x;
  const int b = blockIdx.x;
  const int q = t >> 6;       // wave = h-tile 0..7
  const int l = t & 63;
  const int g = l >> 4;
  const int lm = l & 15;

  float* bul = (float*)(lds + BUL_OFF);
  float* wel = (float*)(lds + WEL_OFF);
  float* epf = (float*)(lds + EP_OFF);
  float (*alpha)[96] = (float (*)[96])(lds + AL_OFF);

  const float* fbase = feats + (size_t)b * NPG * D;

  // ---- phase 1: stage feats -> LDS bf16 swizzled (rows 91..95 zeroed); bu; We; ep=0
  #pragma unroll 1
  for (int i = 0; i < 3; ++i) {
    int c = t + i * 512;              // 1536 chunks of 8 bf16
    int r = c >> 4, d0 = (c & 15) * 8;
    uint4 pk4;
    if (r < NPG) {
      const float* src = fbase + r * D + d0;
      float4 f0 = *(const float4*)(src);
      float4 f1 = *(const float4*)(src + 4);
      pk4.x = bf16pk(f0.x, f0.y);
      pk4.y = bf16pk(f0.z, f0.w);
      pk4.z = bf16pk(f1.x, f1.y);
      pk4.w = bf16pk(f1.z, f1.w);
    } else {
      pk4.x = 0u; pk4.y = 0u; pk4.z = 0u; pk4.w = 0u;
    }
    int off = r * 256 + ((d0 * 2) ^ ((r & 7) << 4));
    *(uint4*)(lds + FE_OFF + off) = pk4;
  }
  if (t < 384) {
    bul[t] = bu[t];
    wel[t] = We[t];
  }
  if (t < 288) {                      // zero ep[3][96] (1152 floats, float4 x 288)
    float4 z4 = {0.f, 0.f, 0.f, 0.f};
    ((float4*)epf)[t] = z4;
  }
  __syncthreads();                    // barrier 1

  // ---- phase 2: 3 orders, completely barrier-free
  const int swz = (lm & 7) << 4;
  #pragma unroll 1
  for (int o = 0; o < 3; ++o) {
    // fv mini-GEMM: B = this group's own last row (49/74/90), lane-uniform ->
    // every output column identical; lane (g,lm) keeps z[r] for h=q*16+g*4+r.
    const int frow = (o == 0) ? 49 : (o == 1) ? 74 : 90;
    const int fswz = (frow & 7) << 4;
    f32x4 z = {0.f, 0.f, 0.f, 0.f};
    #pragma unroll
    for (int kk = 0; kk < 4; ++kk) {
      short8 av = *(const short8*)&wpk[(size_t)(12 + o * 4 + kk) * 512 + (q * 16 + lm) * 4 + g];
      short8 bv = *(const short8*)(lds + FE_OFF + frow * 256 + ((kk * 64 + g * 16) ^ fswz));
      z = __builtin_amdgcn_mfma_f32_16x16x32_bf16(av, bv, z, 0, 0, 0);
    }
    f32x4 bu4 = *(const f32x4*)&bul[o * 128 + q * 16 + g * 4];
    float bias[4];
    bias[0] = z[0] + bu4[0]; bias[1] = z[1] + bu4[1];
    bias[2] = z[2] + bu4[2]; bias[3] = z[3] + bu4[3];
    f32x4 ww = *(const f32x4*)&wel[o * 128 + q * 16 + g * 4];

    // A-fragments hoisted for both node-halves
    short8 a[4];
    #pragma unroll
    for (int kk = 0; kk < 4; ++kk)
      a[kk] = *(const short8*)&wpk[(size_t)(o * 4 + kk) * 512 + (q * 16 + lm) * 4 + g];

    #pragma unroll 1
    for (int nh = 0; nh < 2; ++nh) {
      f32x4 acc[3];
      #pragma unroll
      for (int j = 0; j < 3; ++j) acc[j] = (f32x4){0.f, 0.f, 0.f, 0.f};

      __builtin_amdgcn_s_setprio(1);
      #pragma unroll
      for (int kk = 0; kk < 4; ++kk) {
        const int cb = kk * 64 + g * 16;
        #pragma unroll
        for (int j = 0; j < 3; ++j) {
          const int nt = nh * 3 + j;
          short8 bv = *(const short8*)(lds + FE_OFF + (nt * 16 + lm) * 256 + (cb ^ swz));
          acc[j] = __builtin_amdgcn_mfma_f32_16x16x32_bf16(a[kk], bv, acc[j], 0, 0, 0);
        }
      }
      __builtin_amdgcn_s_setprio(0);
      // epilogue: D row = g*4+r (h), col = lm (node); e-partial per lane over
      // its 4 r's, then ONE ds_add_f32 (4 g-lanes share an address).
      #pragma unroll
      for (int j = 0; j < 3; ++j) {
        float e = sigf(acc[j][0] + bias[0]) * ww[0]
                + sigf(acc[j][1] + bias[1]) * ww[1]
                + sigf(acc[j][2] + bias[2]) * ww[2]
                + sigf(acc[j][3] + bias[3]) * ww[3];
        atomicAdd(&epf[o * 96 + (nh * 3 + j) * 16 + lm], e);
      }
    }
  }

  // ---- T14 prefetch: weighted-sum feats loads issued before the barrier
  const int hw = t >> 5;              // 0..15
  const int d4 = (t & 31) * 4;
  float4 pf[6];
  #pragma unroll
  for (int i = 0; i < 6; ++i) {
    int n = hw + 16 * i;
    if (n < NPG) pf[i] = *(const float4*)(fbase + n * D + d4);
  }
  __syncthreads();                    // barrier 2: ep complete & visible

  // ---- softmax per order (wave o handles order o; rows >= 91 masked)
  if (q < 3) {
    const int o = q;
    const int n1 = l, n2 = l + 64;
    float e1 = (n1 < NPG) ? epf[o * 96 + n1] : -1e30f;
    float e2 = (n2 < NPG) ? epf[o * 96 + n2] : -1e30f;
    float mx = fmaxf(e1, e2);
    #pragma unroll
    for (int m = 1; m < 64; m <<= 1) mx = fmaxf(mx, __shfl_xor(mx, m));
    float x1 = (n1 < NPG) ? __expf(e1 - mx) : 0.f;
    float x2 = (n2 < NPG) ? __expf(e2 - mx) : 0.f;
    float s = x1 + x2;
    #pragma unroll
    for (int m = 1; m < 64; m <<= 1) s += __shfl_xor(s, m);
    float inv = __builtin_amdgcn_rcpf(s);
    if (n1 < NPG) alpha[o][n1] = x1 * inv;
    if (n2 < NPG) alpha[o][n2] = x2 * inv;
  }
  __syncthreads();                    // barrier 3: alpha visible

  // ---- weighted sum: consume prefetched pf[], alpha from LDS
  {
    float a0x = 0.f, a0y = 0.f, a0z = 0.f, a0w = 0.f;
    float a1x = 0.f, a1y = 0.f, a1z = 0.f, a1w = 0.f;
    float a2x = 0.f, a2y = 0.f, a2z = 0.f, a2w = 0.f;
    #pragma unroll
    for (int i = 0; i < 6; ++i) {
      int n = hw + 16 * i;
      if (n < NPG) {
        float al0 = alpha[0][n], al1 = alpha[1][n], al2 = alpha[2][n];
        a0x += pf[i].x * al0; a0y += pf[i].y * al0; a0z += pf[i].z * al0; a0w += pf[i].w * al0;
        a1x += pf[i].x * al1; a1y += pf[i].y * al1; a1z += pf[i].z * al1; a1w += pf[i].w * al1;
        a2x += pf[i].x * al2; a2y += pf[i].y * al2; a2z += pf[i].z * al2; a2w += pf[i].w * al2;
      }
    }
    // fold the two half-waves of this wave
    a0x += __shfl_xor(a0x, 32); a0y += __shfl_xor(a0y, 32);
    a0z += __shfl_xor(a0z, 32); a0w += __shfl_xor(a0w, 32);
    a1x += __shfl_xor(a1x, 32); a1y += __shfl_xor(a1y, 32);
    a1z += __shfl_xor(a1z, 32); a1w += __shfl_xor(a1w, 32);
    a2x += __shfl_xor(a2x, 32); a2y += __shfl_xor(a2y, 32);
    a2z += __shfl_xor(a2z, 32); a2w += __shfl_xor(a2w, 32);
    float* part = (float*)(lds + FE_OFF);   // [8][384] f32, overlays dead feats tile
    if (l < 32) {
      float4 s0 = {a0x, a0y, a0z, a0w};
      float4 s1 = {a1x, a1y, a1z, a1w};
      float4 s2 = {a2x, a2y, a2z, a2w};
      *(float4*)&part[q * 384 + 0 * 128 + d4] = s0;
      *(float4*)&part[q * 384 + 1 * 128 + d4] = s1;
      *(float4*)&part[q * 384 + 2 * 128 + d4] = s2;
    }
  }
  __syncthreads();                    // barrier 4: part visible
  if (t < 384) {
    const float* part = (const float*)(lds + FE_OFF);
    float s = 0.f;
    #pragma unroll
    for (int j = 0; j < 8; ++j) s += part[j * 384 + t];
    out[(size_t)b * 384 + t] = s;
  }
}

extern "C" void kernel_launch(void* const* d_in, const int* in_sizes, int n_in,
                              void* d_out, int out_size, void* d_ws, size_t ws_size,
                              hipStream_t stream) {
  const float* feats = (const float*)d_in[0];
  const float* Wu    = (const float*)d_in[1];
  const float* bu    = (const float*)d_in[2];
  const float* Wv    = (const float*)d_in[3];
  const float* We    = (const float*)d_in[4];
  float* out = (float*)d_out;
  uint4* wpk = (uint4*)d_ws;          // 24*512*16 = 192 KB

  w_pack<<<24, 256, 0, stream>>>(Wu, Wv, wpk);
  sihg_main<<<NB, 512, 0, stream>>>(feats, wpk, bu, We, out);
}

// Round 17
// 60.227 us; speedup vs baseline: 2.3011x; 2.3011x over previous
//
#include <hip/hip_runtime.h>
#include <hip/hip_bf16.h>
#include <stdint.h>

#define NB 2048      // groups
#define D 128
#define NPG 91

typedef __attribute__((ext_vector_type(8))) short short8;
typedef __attribute__((ext_vector_type(4))) float f32x4;

__device__ __forceinline__ unsigned bf16pk(float a, float b) {
  __hip_bfloat162 h2 = __float22bfloat162_rn(make_float2(a, b));
  return *reinterpret_cast<unsigned*>(&h2);   // v_cvt_pk_bf16_f32
}

__device__ __forceinline__ float sigf(float x) {
  float e = __expf(-x);
  return __builtin_amdgcn_rcpf(1.0f + e);     // v_rcp_f32, ~1ulp
}

// K0: pack Wu (units 0..11) and Wv (units 12..23) transposed to bf16 in MFMA
// A-fragment order (flipped GEMM):
// wpk[u*512 + row*4 + g] (uint4) = 8 bf16 of W[o][kk*32+g*8 + 0..7][row],
// u = o*4+kk (Wu) or 12 + o*4+kk (Wv).
__global__ void w_pack(const float* __restrict__ Wu,
                       const float* __restrict__ Wv,
                       uint4* __restrict__ wpk) {
  const int u = blockIdx.x;
  const float* W = (u < 12) ? Wu : Wv;
  const int uu = (u < 12) ? u : u - 12;
  const int o = uu >> 2, kk = uu & 3;
  const int t = threadIdx.x;
  #pragma unroll
  for (int i = 0; i < 2; ++i) {
    int idx = i * 256 + t;              // 0..511
    int row = idx >> 2, g = idx & 3;
    const float* src = W + (size_t)o * D * D + (kk * 32 + g * 8) * D + row;
    uint4 pk;
    pk.x = bf16pk(src[0 * D], src[1 * D]);
    pk.y = bf16pk(src[2 * D], src[3 * D]);
    pk.z = bf16pk(src[4 * D], src[5 * D]);
    pk.w = bf16pk(src[6 * D], src[7 * D]);
    wpk[(size_t)u * 512 + idx] = pk;
  }
}

// K1: one block per group, 512 threads / 8 waves, (512,8) [<=44 total regs
// proven no-spill, 4 blocks/CU]. Wave q owns h-tile q (R14 layout).
// fv bias in-register; barrier-free o-loop with s_setprio(1) around the main
// MFMA cluster (waves desync across nh/o -> role diversity); softmax without
// max-subtraction (|e| <= sum|We| ~ 10, fp32-safe); T14 prefetch of
// weighted-sum loads.
__global__ __launch_bounds__(512, 8) void sihg_main(
    const float* __restrict__ feats,
    const uint4* __restrict__ wpk,
    const float* __restrict__ bu,
    const float* __restrict__ We,
    float* __restrict__ out) {
  __shared__ __align__(16) char lds[38016];
  constexpr int FE_OFF  = 0;      // 24576: feats bf16 [96]x256B swizzled; later part[8][384]
  constexpr int BUL_OFF = 24576;  // 1536: f32[3][128] bu
  constexpr int WEL_OFF = 26112;  // 1536: f32[3][128] We
  constexpr int EP_OFF  = 27648;  // 9216: f32[8][3][96] e-partials per h-tile wave
  constexpr int AL_OFF  = 36864;  // 1152: f32[3][96] alpha

  const int t = threadIdx.x;
  const int b = blockIdx.x;
  const int q = t >> 6;       // wave = h-tile 0..7
  const int l = t & 63;
  const int g = l >> 4;
  const int lm = l & 15;

  float* bul = (float*)(lds + BUL_OFF);
  float* wel = (float*)(lds + WEL_OFF);
  float (*ep)[3][96] = (float (*)[3][96])(lds + EP_OFF);
  float (*alpha)[96] = (float (*)[96])(lds + AL_OFF);

  const float* fbase = feats + (size_t)b * NPG * D;

  // ---- phase 1: stage feats -> LDS bf16 swizzled (rows 91..95 zeroed); bu; We
  #pragma unroll 1
  for (int i = 0; i < 3; ++i) {
    int c = t + i * 512;              // 1536 chunks of 8 bf16
    int r = c >> 4, d0 = (c & 15) * 8;
    uint4 pk4;
    if (r < NPG) {
      const float* src = fbase + r * D + d0;
      float4 f0 = *(const float4*)(src);
      float4 f1 = *(const float4*)(src + 4);
      pk4.x = bf16pk(f0.x, f0.y);
      pk4.y = bf16pk(f0.z, f0.w);
      pk4.z = bf16pk(f1.x, f1.y);
      pk4.w = bf16pk(f1.z, f1.w);
    } else {
      pk4.x = 0u; pk4.y = 0u; pk4.z = 0u; pk4.w = 0u;
    }
    int off = r * 256 + ((d0 * 2) ^ ((r & 7) << 4));
    *(uint4*)(lds + FE_OFF + off) = pk4;
  }
  if (t < 384) {
    bul[t] = bu[t];
    wel[t] = We[t];
  }
  __syncthreads();                    // barrier 1 (only one before softmax)

  // ---- phase 2: 3 orders, completely barrier-free
  const int swz = (lm & 7) << 4;
  #pragma unroll 1
  for (int o = 0; o < 3; ++o) {
    // fv mini-GEMM: B = this group's own last row (49/74/90), lane-uniform ->
    // every output column identical; lane (g,lm) keeps z[r] for h=q*16+g*4+r.
    const int frow = (o == 0) ? 49 : (o == 1) ? 74 : 90;
    const int fswz = (frow & 7) << 4;
    f32x4 z = {0.f, 0.f, 0.f, 0.f};
    #pragma unroll
    for (int kk = 0; kk < 4; ++kk) {
      short8 av = *(const short8*)&wpk[(size_t)(12 + o * 4 + kk) * 512 + (q * 16 + lm) * 4 + g];
      short8 bv = *(const short8*)(lds + FE_OFF + frow * 256 + ((kk * 64 + g * 16) ^ fswz));
      z = __builtin_amdgcn_mfma_f32_16x16x32_bf16(av, bv, z, 0, 0, 0);
    }
    f32x4 bu4 = *(const f32x4*)&bul[o * 128 + q * 16 + g * 4];
    float bias[4];
    bias[0] = z[0] + bu4[0]; bias[1] = z[1] + bu4[1];
    bias[2] = z[2] + bu4[2]; bias[3] = z[3] + bu4[3];
    f32x4 ww = *(const f32x4*)&wel[o * 128 + q * 16 + g * 4];

    // A-fragments hoisted for both node-halves
    short8 a[4];
    #pragma unroll
    for (int kk = 0; kk < 4; ++kk)
      a[kk] = *(const short8*)&wpk[(size_t)(o * 4 + kk) * 512 + (q * 16 + lm) * 4 + g];

    #pragma unroll 1
    for (int nh = 0; nh < 2; ++nh) {
      f32x4 acc[3];
      #pragma unroll
      for (int j = 0; j < 3; ++j) acc[j] = (f32x4){0.f, 0.f, 0.f, 0.f};

      __builtin_amdgcn_s_setprio(1);
      #pragma unroll
      for (int kk = 0; kk < 4; ++kk) {
        const int cb = kk * 64 + g * 16;
        #pragma unroll
        for (int j = 0; j < 3; ++j) {
          const int nt = nh * 3 + j;
          short8 bv = *(const short8*)(lds + FE_OFF + (nt * 16 + lm) * 256 + (cb ^ swz));
          acc[j] = __builtin_amdgcn_mfma_f32_16x16x32_bf16(a[kk], bv, acc[j], 0, 0, 0);
        }
      }
      __builtin_amdgcn_s_setprio(0);
      // epilogue: D row = g*4+r (h), col = lm (node)
      #pragma unroll
      for (int j = 0; j < 3; ++j) {
        float e = sigf(acc[j][0] + bias[0]) * ww[0]
                + sigf(acc[j][1] + bias[1]) * ww[1]
                + sigf(acc[j][2] + bias[2]) * ww[2]
                + sigf(acc[j][3] + bias[3]) * ww[3];
        e += __shfl_xor(e, 16);
        e += __shfl_xor(e, 32);
        if (l < 16) ep[q][o][(nh * 3 + j) * 16 + l] = e;
      }
    }
  }

  // ---- T14 prefetch: weighted-sum feats loads issued before the barrier
  const int hw = t >> 5;              // 0..15
  const int d4 = (t & 31) * 4;
  float4 pf[6];
  #pragma unroll
  for (int i = 0; i < 6; ++i) {
    int n = hw + 16 * i;
    if (n < NPG) pf[i] = *(const float4*)(fbase + n * D + d4);
  }
  __syncthreads();                    // barrier 2: ep visible

  // ---- softmax per order, NO max-subtraction (|e| <= sum|We| ~ 10, safe)
  if (q < 3) {
    const int o = q;
    const int n1 = l, n2 = l + 64;
    float x1 = 0.f, x2 = 0.f;
    if (n1 < NPG) {
      float e1 = 0.f;
      #pragma unroll
      for (int j = 0; j < 8; ++j) e1 += ep[j][o][n1];
      x1 = __expf(e1);
    }
    if (n2 < NPG) {
      float e2 = 0.f;
      #pragma unroll
      for (int j = 0; j < 8; ++j) e2 += ep[j][o][n2];
      x2 = __expf(e2);
    }
    float s = x1 + x2;
    #pragma unroll
    for (int m = 1; m < 64; m <<= 1) s += __shfl_xor(s, m);
    float inv = __builtin_amdgcn_rcpf(s);
    if (n1 < NPG) alpha[o][n1] = x1 * inv;
    if (n2 < NPG) alpha[o][n2] = x2 * inv;
  }
  __syncthreads();                    // barrier 3: alpha visible

  // ---- weighted sum: consume prefetched pf[], alpha from LDS
  {
    float a0x = 0.f, a0y = 0.f, a0z = 0.f, a0w = 0.f;
    float a1x = 0.f, a1y = 0.f, a1z = 0.f, a1w = 0.f;
    float a2x = 0.f, a2y = 0.f, a2z = 0.f, a2w = 0.f;
    #pragma unroll
    for (int i = 0; i < 6; ++i) {
      int n = hw + 16 * i;
      if (n < NPG) {
        float al0 = alpha[0][n], al1 = alpha[1][n], al2 = alpha[2][n];
        a0x += pf[i].x * al0; a0y += pf[i].y * al0; a0z += pf[i].z * al0; a0w += pf[i].w * al0;
        a1x += pf[i].x * al1; a1y += pf[i].y * al1; a1z += pf[i].z * al1; a1w += pf[i].w * al1;
        a2x += pf[i].x * al2; a2y += pf[i].y * al2; a2z += pf[i].z * al2; a2w += pf[i].w * al2;
      }
    }
    // fold the two half-waves of this wave
    a0x += __shfl_xor(a0x, 32); a0y += __shfl_xor(a0y, 32);
    a0z += __shfl_xor(a0z, 32); a0w += __shfl_xor(a0w, 32);
    a1x += __shfl_xor(a1x, 32); a1y += __shfl_xor(a1y, 32);
    a1z += __shfl_xor(a1z, 32); a1w += __shfl_xor(a1w, 32);
    a2x += __shfl_xor(a2x, 32); a2y += __shfl_xor(a2y, 32);
    a2z += __shfl_xor(a2z, 32); a2w += __shfl_xor(a2w, 32);
    float* part = (float*)(lds + FE_OFF);   // [8][384] f32, overlays dead feats tile
    if (l < 32) {
      float4 s0 = {a0x, a0y, a0z, a0w};
      float4 s1 = {a1x, a1y, a1z, a1w};
      float4 s2 = {a2x, a2y, a2z, a2w};
      *(float4*)&part[q * 384 + 0 * 128 + d4] = s0;
      *(float4*)&part[q * 384 + 1 * 128 + d4] = s1;
      *(float4*)&part[q * 384 + 2 * 128 + d4] = s2;
    }
  }
  __syncthreads();                    // barrier 4: part visible
  if (t < 384) {
    const float* part = (const float*)(lds + FE_OFF);
    float s = 0.f;
    #pragma unroll
    for (int j = 0; j < 8; ++j) s += part[j * 384 + t];
    out[(size_t)b * 384 + t] = s;
  }
}

extern "C" void kernel_launch(void* const* d_in, const int* in_sizes, int n_in,
                              void* d_out, int out_size, void* d_ws, size_t ws_size,
                              hipStream_t stream) {
  const float* feats = (const float*)d_in[0];
  const float* Wu    = (const float*)d_in[1];
  const float* bu    = (const float*)d_in[2];
  const float* Wv    = (const float*)d_in[3];
  const float* We    = (const float*)d_in[4];
  float* out = (float*)d_out;
  uint4* wpk = (uint4*)d_ws;          // 24*512*16 = 192 KB

  w_pack<<<24, 256, 0, stream>>>(Wu, Wv, wpk);
  sihg_main<<<NB, 512, 0, stream>>>(feats, wpk, bu, We, out);
}